// Round 2
// baseline (755.566 us; speedup 1.0000x reference)
//
#include <hip/hip_runtime.h>
#include <stdint.h>

// ---------------------------------------------------------------------------
// Attention: out = softmax(Q K^T) V,  N=8, S=2048, E=512, fp32 in/out.
// R2: BQ=32 (512 blocks -> 2 blocks/CU), BK=64, 2 barriers/K-tile.
// K and V^T operands loaded global->register (no LDS staging, L1/L2-served).
// LDS only for: 4-way e-split partial-S reduce, softmax state, P transpose.
// Numerics: bf16x2 split QK^T (hh+lh+hl), bf16 PV, fp32 accumulate.
// ---------------------------------------------------------------------------

typedef __attribute__((ext_vector_type(8))) short   short8;   // 8 x bf16
typedef __attribute__((ext_vector_type(4))) float   floatx4;  // MFMA acc

#define NBATCH 8
#define SEQ    2048
#define EDIM   512
static constexpr size_t NE = (size_t)NBATCH * SEQ * EDIM;  // 8388608 elems/tensor

__device__ __forceinline__ uint16_t f32_to_bf16_rne(float f) {
  uint32_t u = __float_as_uint(f);
  uint32_t r = u + 0x7FFFu + ((u >> 16) & 1u);
  return (uint16_t)(r >> 16);
}
__device__ __forceinline__ float bf16_to_f32(uint16_t h) {
  return __uint_as_float(((uint32_t)h) << 16);
}

// --- pre-pass 1: split Q and K into hi/lo bf16 planes. 8 elems/thread, 16B stores.
__global__ void convert_split_qk(const float* __restrict__ q, const float* __restrict__ k,
                                 uint16_t* __restrict__ qhi, uint16_t* __restrict__ qlo,
                                 uint16_t* __restrict__ khi, uint16_t* __restrict__ klo) {
  size_t i = ((size_t)blockIdx.x * blockDim.x + threadIdx.x) * 8;
  const float* src; uint16_t* dhi; uint16_t* dlo;
  if (i < NE) { src = q; dhi = qhi; dlo = qlo; }
  else        { i -= NE; src = k; dhi = khi; dlo = klo; }
  float4 a = *reinterpret_cast<const float4*>(src + i);
  float4 b = *reinterpret_cast<const float4*>(src + i + 4);
  union { uint16_t u[8]; short8 v; } H, L;
  float x[8] = {a.x, a.y, a.z, a.w, b.x, b.y, b.z, b.w};
#pragma unroll
  for (int j = 0; j < 8; j++) {
    H.u[j] = f32_to_bf16_rne(x[j]);
    L.u[j] = f32_to_bf16_rne(x[j] - bf16_to_f32(H.u[j]));
  }
  *reinterpret_cast<short8*>(dhi + i) = H.v;
  *reinterpret_cast<short8*>(dlo + i) = L.v;
}

// --- pre-pass 2: V[n][k][e] -> vt[n][e][k] bf16. 64x64 tiles, 256 thr, 16B stores.
__global__ void transpose_v_bf16(const float* __restrict__ v, uint16_t* __restrict__ vt) {
  __shared__ float tile[64][65];
  const int tid = threadIdx.x;
  const int b = blockIdx.x;                 // 8 n * 32 kt * 8 et = 2048
  const int n = b >> 8, rem = b & 255;
  const int kt = rem >> 3, et = rem & 7;
  {
    const int lr = tid >> 4, lc = (tid & 15) * 4;
    const float* src = v + ((size_t)(n * SEQ + kt * 64 + lr)) * EDIM + et * 64 + lc;
#pragma unroll
    for (int i = 0; i < 4; i++) {
      float4 x = *reinterpret_cast<const float4*>(src + (size_t)i * 16 * EDIM);
      tile[lr + 16 * i][lc + 0] = x.x; tile[lr + 16 * i][lc + 1] = x.y;
      tile[lr + 16 * i][lc + 2] = x.z; tile[lr + 16 * i][lc + 3] = x.w;
    }
  }
  __syncthreads();
  {
    const int er = tid >> 3, kc = (tid & 7) * 8;
#pragma unroll
    for (int i = 0; i < 2; i++) {
      const int e = er + 32 * i;
      union { uint16_t u[8]; short8 v8; } o;
#pragma unroll
      for (int j = 0; j < 8; j++) o.u[j] = f32_to_bf16_rne(tile[kc + j][e]);
      uint16_t* dst = vt + ((size_t)(n * EDIM + et * 64 + e)) * SEQ + kt * 64 + kc;
      *reinterpret_cast<short8*>(dst) = o.v8;
    }
  }
}

// ---------------------------------------------------------------------------
// Fused flash attention. Grid 512 = (n = blk&7, qtile = blk>>3), 512 thr / 8 waves.
// BQ=32, BK=64, 32 K-tiles. Wave (h = w&1: 16-q strip, es = w>>1: 128-e quarter).
// S-phase: wave computes 16q x 64k partial (its e-quarter) -> s_part[es];
//          K B-frags straight from global (khi/klo), Q frags in registers.
// softmax: 512 thr = 32 rows x 16, 4-plane combine, shfl row-reduce, P->LDS bf16.
// PV: wave owns 64-e slice [w*64, w*64+64); V^T B-frags straight from global.
// 2 __syncthreads per K-tile. LDS = 34816 + 4608 + 384 = 39808 B -> 2 blocks/CU.
// __launch_bounds__(512,4): VGPR <= 128 so both blocks are resident.
// ---------------------------------------------------------------------------
__launch_bounds__(512, 4)
__global__ void attn_fused(const uint16_t* __restrict__ qhi, const uint16_t* __restrict__ qlo,
                           const uint16_t* __restrict__ khi, const uint16_t* __restrict__ klo,
                           const uint16_t* __restrict__ vt, float* __restrict__ out) {
  __shared__ float    s_part[4][32][68];   // e-quarter partial scores (fp32)
  __shared__ uint16_t p_lds[32][72];       // P bf16, row-major (144B stride, 16B-aligned)
  __shared__ float    m_lds[32], l_lds[32], a_lds[32];

  const int tid  = threadIdx.x;
  const int lane = tid & 63, w = tid >> 6;
  const int m15  = lane & 15, q4 = lane >> 4;
  const int n    = blockIdx.x & 7, qt = blockIdx.x >> 3;
  const int q0   = qt * 32;
  const int h    = w & 1, es = w >> 1;

  if (tid < 32) { m_lds[tid] = -3.0e38f; l_lds[tid] = 0.0f; }

  // ---- Q fragments resident in registers: [e-chunk][hi/lo], 32 VGPRs
  short8 qf[4][2];
  {
    const int row = q0 + h * 16 + m15;
    const uint16_t* bh = qhi + ((size_t)n * SEQ + row) * EDIM + es * 128 + q4 * 8;
    const uint16_t* bl = qlo + ((size_t)n * SEQ + row) * EDIM + es * 128 + q4 * 8;
#pragma unroll
    for (int c = 0; c < 4; c++) {
      qf[c][0] = *reinterpret_cast<const short8*>(bh + c * 32);
      qf[c][1] = *reinterpret_cast<const short8*>(bl + c * 32);
    }
  }

  floatx4 oacc[2][4];                       // [q-strip][e-subtile], 32 VGPRs
#pragma unroll
  for (int s = 0; s < 2; s++)
#pragma unroll
    for (int j = 0; j < 4; j++) oacc[s][j] = (floatx4){0.f, 0.f, 0.f, 0.f};

  // K B-frag offsets (elements), advance by 64*EDIM per K-tile
  uint32_t koff[4];
#pragma unroll
  for (int ks = 0; ks < 4; ks++)
    koff[ks] = ((uint32_t)n * SEQ + ks * 16 + m15) * EDIM + es * 128 + q4 * 8;
  // V^T B-frag offsets, advance by 64 per K-tile
  uint32_t voff[4];
#pragma unroll
  for (int j = 0; j < 4; j++)
    voff[j] = ((uint32_t)n * EDIM + w * 64 + j * 16 + m15) * SEQ + q4 * 8;

  __syncthreads();                          // covers m_lds/l_lds init

  for (int kt = 0; kt < 32; kt++) {
    // ---- S phase: 16q x 64k, this wave's 128-e quarter, K direct from global
    floatx4 sacc[4];
#pragma unroll
    for (int ks = 0; ks < 4; ks++) sacc[ks] = (floatx4){0.f, 0.f, 0.f, 0.f};
#pragma unroll
    for (int c = 0; c < 4; c++) {
#pragma unroll
      for (int ks = 0; ks < 4; ks++) {
        short8 bh = *reinterpret_cast<const short8*>(khi + koff[ks] + c * 32);
        short8 bl = *reinterpret_cast<const short8*>(klo + koff[ks] + c * 32);
        sacc[ks] = __builtin_amdgcn_mfma_f32_16x16x32_bf16(qf[c][0], bh, sacc[ks], 0, 0, 0);
        sacc[ks] = __builtin_amdgcn_mfma_f32_16x16x32_bf16(qf[c][1], bh, sacc[ks], 0, 0, 0);
        sacc[ks] = __builtin_amdgcn_mfma_f32_16x16x32_bf16(qf[c][0], bl, sacc[ks], 0, 0, 0);
      }
    }
    // write partials: row = h*16+q4*4+r, col = ks*16+m15  (2-way bank alias: free)
#pragma unroll
    for (int ks = 0; ks < 4; ks++)
#pragma unroll
      for (int r = 0; r < 4; r++)
        s_part[es][h * 16 + q4 * 4 + r][ks * 16 + m15] = sacc[ks][r];
    __syncthreads();

    // ---- softmax: 32 rows x 16 threads, 4 cols each
    {
      const int r = tid >> 4, sub = tid & 15;
      floatx4 sv = *reinterpret_cast<floatx4*>(&s_part[0][r][sub * 4]);
      sv += *reinterpret_cast<floatx4*>(&s_part[1][r][sub * 4]);
      sv += *reinterpret_cast<floatx4*>(&s_part[2][r][sub * 4]);
      sv += *reinterpret_cast<floatx4*>(&s_part[3][r][sub * 4]);
      float mx = fmaxf(fmaxf(sv[0], sv[1]), fmaxf(sv[2], sv[3]));
#pragma unroll
      for (int o = 1; o < 16; o <<= 1) mx = fmaxf(mx, __shfl_xor(mx, o));
      const float mo = m_lds[r];
      const float mn = fmaxf(mo, mx);
      floatx4 p;
      p[0] = __expf(sv[0] - mn); p[1] = __expf(sv[1] - mn);
      p[2] = __expf(sv[2] - mn); p[3] = __expf(sv[3] - mn);
      float rs = p[0] + p[1] + p[2] + p[3];
#pragma unroll
      for (int o = 1; o < 16; o <<= 1) rs += __shfl_xor(rs, o);
      if (sub == 0) {
        const float al = __expf(mo - mn);
        a_lds[r] = al; m_lds[r] = mn; l_lds[r] = l_lds[r] * al + rs;
      }
      ushort4 pu;
      pu.x = f32_to_bf16_rne(p[0]); pu.y = f32_to_bf16_rne(p[1]);
      pu.z = f32_to_bf16_rne(p[2]); pu.w = f32_to_bf16_rne(p[3]);
      *reinterpret_cast<ushort4*>(&p_lds[r][sub * 4]) = pu;
    }
    __syncthreads();

    // ---- O rescale + PV (V^T direct from global)
    {
      floatx4 al0 = *reinterpret_cast<floatx4*>(&a_lds[q4 * 4]);
      floatx4 al1 = *reinterpret_cast<floatx4*>(&a_lds[16 + q4 * 4]);
#pragma unroll
      for (int j = 0; j < 4; j++) { oacc[0][j] *= al0; oacc[1][j] *= al1; }
    }
#pragma unroll
    for (int kstep = 0; kstep < 2; kstep++) {
      short8 pf0 = *reinterpret_cast<const short8*>(&p_lds[m15][kstep * 32 + q4 * 8]);
      short8 pf1 = *reinterpret_cast<const short8*>(&p_lds[16 + m15][kstep * 32 + q4 * 8]);
#pragma unroll
      for (int j = 0; j < 4; j++) {
        short8 vf = *reinterpret_cast<const short8*>(vt + voff[j] + kstep * 32);
        oacc[0][j] = __builtin_amdgcn_mfma_f32_16x16x32_bf16(pf0, vf, oacc[0][j], 0, 0, 0);
        oacc[1][j] = __builtin_amdgcn_mfma_f32_16x16x32_bf16(pf1, vf, oacc[1][j], 0, 0, 0);
      }
    }
#pragma unroll
    for (int ks = 0; ks < 4; ks++) koff[ks] += 64 * EDIM;
#pragma unroll
    for (int j = 0; j < 4; j++)  voff[j] += 64;
  }

  // ---- epilogue: divide by l, store fp32 (l_lds final after last in-loop barrier)
  floatx4 lv0 = *reinterpret_cast<floatx4*>(&l_lds[q4 * 4]);
  floatx4 lv1 = *reinterpret_cast<floatx4*>(&l_lds[16 + q4 * 4]);
#pragma unroll
  for (int s = 0; s < 2; s++) {
    floatx4 lv = s ? lv1 : lv0;
#pragma unroll
    for (int j = 0; j < 4; j++) {
#pragma unroll
      for (int r = 0; r < 4; r++) {
        const int row = s * 16 + q4 * 4 + r;
        out[((size_t)n * SEQ + q0 + row) * EDIM + w * 64 + j * 16 + m15] = oacc[s][j][r] / lv[r];
      }
    }
  }
}

// ---------------------------------------------------------------------------
// Fallback (ws too small): fp32 VALU attention, one block per query row.
// ---------------------------------------------------------------------------
__global__ void attn_fallback(const float* __restrict__ q, const float* __restrict__ k,
                              const float* __restrict__ v, float* __restrict__ out) {
  __shared__ float qrow[EDIM];
  __shared__ float sc[SEQ];
  __shared__ float red[16];
  const int tid = threadIdx.x;                    // 256
  const int n = blockIdx.x >> 11, qi = blockIdx.x & 2047;
  const int wv = tid >> 6, ln = tid & 63;
  const float* qp = q + ((size_t)n * SEQ + qi) * EDIM;
  for (int e = tid; e < EDIM; e += 256) qrow[e] = qp[e];
  __syncthreads();
  for (int kk = wv; kk < SEQ; kk += 4) {
    const float* kp = k + ((size_t)n * SEQ + kk) * EDIM;
    float s = 0.f;
    for (int e = ln; e < EDIM; e += 64) s = fmaf(qrow[e], kp[e], s);
    for (int o = 32; o > 0; o >>= 1) s += __shfl_down(s, o);
    if (ln == 0) sc[kk] = s;
  }
  __syncthreads();
  float mx = -3.0e38f;
  for (int kk = tid; kk < SEQ; kk += 256) mx = fmaxf(mx, sc[kk]);
  for (int o = 32; o > 0; o >>= 1) mx = fmaxf(mx, __shfl_down(mx, o));
  if (ln == 0) red[wv] = mx;
  __syncthreads();
  if (tid == 0) {
    float m2 = red[0];
    for (int i = 1; i < 4; i++) m2 = fmaxf(m2, red[i]);
    red[8] = m2;
  }
  __syncthreads();
  const float m = red[8];
  float ls = 0.f;
  for (int kk = tid; kk < SEQ; kk += 256) { float p = __expf(sc[kk] - m); sc[kk] = p; ls += p; }
  for (int o = 32; o > 0; o >>= 1) ls += __shfl_down(ls, o);
  if (ln == 0) red[wv] = ls;
  __syncthreads();
  if (tid == 0) { red[9] = red[0] + red[1] + red[2] + red[3]; }
  __syncthreads();
  const float linv = 1.f / red[9];
  for (int e = tid; e < EDIM; e += 256) {
    float acc = 0.f;
    const float* vp = v + ((size_t)n * SEQ) * EDIM + e;
    for (int kk = 0; kk < SEQ; kk++) acc = fmaf(sc[kk], vp[(size_t)kk * EDIM], acc);
    out[((size_t)n * SEQ + qi) * EDIM + e] = acc * linv;
  }
}

extern "C" void kernel_launch(void* const* d_in, const int* in_sizes, int n_in,
                              void* d_out, int out_size, void* d_ws, size_t ws_size,
                              hipStream_t stream) {
  const float* q = (const float*)d_in[0];
  const float* k = (const float*)d_in[1];
  const float* v = (const float*)d_in[2];
  float* out = (float*)d_out;
  const size_t need = 5 * NE * sizeof(uint16_t);   // 83,886,080 B
  if (ws_size >= need) {
    uint16_t* qhi = (uint16_t*)d_ws;
    uint16_t* qlo = qhi + NE;
    uint16_t* khi = qlo + NE;
    uint16_t* klo = khi + NE;
    uint16_t* vtp = klo + NE;
    convert_split_qk<<<8192, 256, 0, stream>>>(q, k, qhi, qlo, khi, klo);
    transpose_v_bf16<<<2048, 256, 0, stream>>>(v, vtp);
    attn_fused<<<512, 512, 0, stream>>>(qhi, qlo, khi, klo, vtp, out);
  } else {
    attn_fallback<<<16384, 256, 0, stream>>>(q, k, v, out);
  }
}

// Round 3
// 321.933 us; speedup vs baseline: 2.3470x; 2.3470x over previous
//
#include <hip/hip_runtime.h>
#include <stdint.h>

// ---------------------------------------------------------------------------
// Attention: out = softmax(Q K^T) V,  N=8, S=2048, E=512, fp32 in/out.
// R3: full fp16 pipeline (single-pass QK^T), operands pre-shuffled into MFMA
// FRAGMENT-LANE ORDER in ws so every A/B fragment is one coalesced 1KB global
// load (wave base + lane*16). No LDS staging of K/V; 2 raw-s_barrier
// syncs/tile (no vmcnt drain) so prefetched loads pipeline across barriers.
// ---------------------------------------------------------------------------

typedef __attribute__((ext_vector_type(8))) _Float16 half8;   // MFMA A/B frag
typedef __attribute__((ext_vector_type(4))) _Float16 half4;
typedef __attribute__((ext_vector_type(4))) float    floatx4; // MFMA C/D frag

#define NBATCH 8
#define SEQ    2048
#define EDIM   512
static constexpr size_t NE = (size_t)NBATCH * SEQ * EDIM;  // 8388608 elems/tensor

// Barrier WITHOUT vmcnt drain: LDS ordering only. Global prefetches stay in
// flight across it; their consumers get compiler-inserted vmcnt waits.
__device__ __forceinline__ void block_sync_lds() {
  asm volatile("s_waitcnt lgkmcnt(0)\n\ts_barrier" ::: "memory");
}

// ---------------------------------------------------------------------------
// Fragment layouts (must match the main kernel exactly):
//  A/B-frag for 16x16x32: lane l holds elems [dim16 = l&15][k = (l>>4)*8 + j].
//  Q/K (dim16 = row, k = e):   xf[((n*128 + rt)*16 + est)*512 + lane*8 + j]
//     rt = row>>4 (0..127), est = e>>5, lane = ((e>>3)&3)*16 + (row&15), j=e&7
//  V   (dim16 = e-col, k = krow within 32-tile):
//     vf[((n*64 + kt)*32 + et)*512 + lane*8 + j]
//     kt = krow>>5, et = e>>4, lane = ((krow>>3)&3)*16 + (e&15), j = krow&7
// ---------------------------------------------------------------------------

// --- pre-pass 1: Q,K fp32 row-major -> fp16 frag order. 1024 blocks x 256.
__global__ void make_frags_qk(const float* __restrict__ q, const float* __restrict__ k,
                              _Float16* __restrict__ qf, _Float16* __restrict__ kf) {
  __shared__ float lds[16][516];
  const int tid = threadIdx.x;
  const int b = blockIdx.x;                 // 2 tensors x 8 n x 64 r32-groups
  const int tensor = b >> 9, n = (b >> 6) & 7, r32 = b & 63;
  const float* src = (tensor ? k : q) + ((size_t)n * SEQ + r32 * 32) * EDIM;
  _Float16* dst = (tensor ? kf : qf) + ((size_t)(n * 128 + r32 * 2) * 16) * 512;
#pragma unroll
  for (int half = 0; half < 2; half++) {
    if (half) __syncthreads();
#pragma unroll
    for (int i = 0; i < 8; i++) {           // stage 16 rows x 512 f32
      int c = i * 256 + tid;                // float4 index within half
      int row = c >> 7, col4 = c & 127;
      float4 x = *reinterpret_cast<const float4*>(src + ((size_t)(half * 16 + row)) * EDIM + col4 * 4);
      *reinterpret_cast<float4*>(&lds[row][col4 * 4]) = x;
    }
    __syncthreads();
#pragma unroll
    for (int i = 0; i < 4; i++) {           // emit 1024 16B frag-chunks
      int fl = i * 256 + tid;               // (est, lane) within this rt
      int est = (fl >> 6) & 15, ln = fl & 63;
      int row = ln & 15, e = est * 32 + (ln >> 4) * 8;
      float4 a = *reinterpret_cast<float4*>(&lds[row][e]);
      float4 bv = *reinterpret_cast<float4*>(&lds[row][e + 4]);
      half8 h;
      h[0] = (_Float16)a.x;  h[1] = (_Float16)a.y;  h[2] = (_Float16)a.z;  h[3] = (_Float16)a.w;
      h[4] = (_Float16)bv.x; h[5] = (_Float16)bv.y; h[6] = (_Float16)bv.z; h[7] = (_Float16)bv.w;
      *reinterpret_cast<half8*>(dst + ((size_t)half * 1024 + fl) * 8) = h;
    }
  }
}

// --- pre-pass 2: V fp32 row-major -> fp16 frag order (B-operand of PV).
__global__ void make_frags_v(const float* __restrict__ v, _Float16* __restrict__ vf) {
  __shared__ float lds[32][260];
  const int tid = threadIdx.x;
  const int b = blockIdx.x;                 // 8 n x 64 kt = 512
  const int n = b >> 6, kt = b & 63;
  const float* src = v + ((size_t)n * SEQ + kt * 32) * EDIM;
  _Float16* dst = vf + ((size_t)(n * 64 + kt) * 32) * 512;
#pragma unroll
  for (int eh = 0; eh < 2; eh++) {          // two 256-e halves
    if (eh) __syncthreads();
#pragma unroll
    for (int i = 0; i < 8; i++) {           // stage 32 rows x 256 f32
      int c = i * 256 + tid;                // float4 index
      int row = c >> 6, col4 = c & 63;
      float4 x = *reinterpret_cast<const float4*>(src + (size_t)row * EDIM + eh * 256 + col4 * 4);
      *reinterpret_cast<float4*>(&lds[row][col4 * 4]) = x;
    }
    __syncthreads();
#pragma unroll
    for (int i = 0; i < 4; i++) {           // emit 1024 chunks (et in this half)
      int fl = i * 256 + tid;               // (et_local, lane)
      int etl = fl >> 6, ln = fl & 63;
      int m15 = ln & 15, q4 = ln >> 4;
      int e_local = etl * 16 + m15;         // e within this 256-half
      half8 h;
#pragma unroll
      for (int j = 0; j < 8; j++) h[j] = (_Float16)lds[q4 * 8 + j][e_local];
      *reinterpret_cast<half8*>(dst + ((size_t)eh * 1024 + fl) * 8) = h;
    }
  }
}

// ---------------------------------------------------------------------------
// Fused flash attention. Grid 256 = (n = blk&7, qt = blk>>3), 512 thr / 8 waves.
// BQ=64, BK=32, 64 K-tiles. Wave = (qh = w&1, ks = (w>>1)&1, eh = w>>2):
//  S-phase: 2 C-tiles (qs = 2qh+s, ks) over its 256-e half; each K frag read by
//  exactly one wave. Q frags in regs. 2-plane partial reduce in LDS.
//  PV: wave owns e-slice [w*64, w*64+64) (et = 4w..4w+3); each V frag 1 wave.
// 2 block_sync_lds per tile. K(t+1) and V(t) prefetched before the barriers,
// consumed after — loads pipeline across (no vmcnt drain at barrier).
// ---------------------------------------------------------------------------
__launch_bounds__(512, 2)
__global__ void attn_fused(const _Float16* __restrict__ qf, const _Float16* __restrict__ kf,
                           const _Float16* __restrict__ vf, float* __restrict__ out) {
  __shared__ float    s_part[2][64][36];   // 2 e-half partial scores
  __shared__ _Float16 p_lds[64][40];       // P fp16 (A-layout source)
  __shared__ float    m_lds[64], l_lds[64], a_lds[64];

  const int tid  = threadIdx.x;
  const int lane = tid & 63, w = tid >> 6;
  const int m15  = lane & 15, q4 = lane >> 4;
  const int n    = blockIdx.x & 7, qt = blockIdx.x >> 3;
  const int qh   = w & 1, ks = (w >> 1) & 1, eh = w >> 2;

  if (tid < 64) { m_lds[tid] = -3.0e38f; l_lds[tid] = 0.0f; }

  // ---- Q fragments resident: qs-strips {2qh, 2qh+1}, e-half eh. 64 VGPRs.
  half8 qfr[2][8];
#pragma unroll
  for (int s = 0; s < 2; s++) {
    const _Float16* qp = qf + ((size_t)((n * 128 + qt * 4 + 2 * qh + s) * 16 + eh * 8)) * 512 + lane * 8;
#pragma unroll
    for (int i = 0; i < 8; i++) qfr[s][i] = *reinterpret_cast<const half8*>(qp + i * 512);
  }

  floatx4 oacc[4][4];                       // [qs][et_local], 64 VGPRs
#pragma unroll
  for (int s = 0; s < 4; s++)
#pragma unroll
    for (int j = 0; j < 4; j++) oacc[s][j] = (floatx4){0.f, 0.f, 0.f, 0.f};

  const _Float16* kptr = kf + ((size_t)((n * 128 + ks) * 16 + eh * 8)) * 512 + lane * 8;
  const _Float16* vptr = vf + ((size_t)(n * 64 * 32 + w * 4)) * 512 + lane * 8;

  half8 kbufA[8], kbufB[8];
#pragma unroll
  for (int i = 0; i < 8; i++) kbufA[i] = *reinterpret_cast<const half8*>(kptr + i * 512);
  kptr += 16384;                            // 2 rt * 16 est * 512

  auto tile_step = [&](half8 (&kcur)[8], half8 (&knxt)[8], int kt) {
    // ---- S: 2 C-tiles, 4 independent 4-long MFMA chains
    floatx4 sacc[2][2];
#pragma unroll
    for (int s = 0; s < 2; s++) { sacc[s][0] = (floatx4){0,0,0,0}; sacc[s][1] = (floatx4){0,0,0,0}; }
#pragma unroll
    for (int i = 0; i < 8; i++) {
      sacc[0][i >> 2] = __builtin_amdgcn_mfma_f32_16x16x32_f16(qfr[0][i], kcur[i], sacc[0][i >> 2], 0, 0, 0);
      sacc[1][i >> 2] = __builtin_amdgcn_mfma_f32_16x16x32_f16(qfr[1][i], kcur[i], sacc[1][i >> 2], 0, 0, 0);
    }
    // ---- prefetch V (this tile) and K (next tile) — consumed after barriers
    half8 vfr[4];
#pragma unroll
    for (int j = 0; j < 4; j++) vfr[j] = *reinterpret_cast<const half8*>(vptr + j * 512);
    vptr += 16384;                          // 32 et * 512
    if (kt < 63) {
#pragma unroll
      for (int i = 0; i < 8; i++) knxt[i] = *reinterpret_cast<const half8*>(kptr + i * 512);
      kptr += 16384;
    }
    // ---- write S partials (C-layout: row=(lane>>4)*4+r, col=lane&15)
#pragma unroll
    for (int s = 0; s < 2; s++)
#pragma unroll
      for (int r = 0; r < 4; r++)
        s_part[eh][(2 * qh + s) * 16 + q4 * 4 + r][ks * 16 + m15] = sacc[s][0][r] + sacc[s][1][r];
    block_sync_lds();                       // b1

    // ---- online softmax: 64 rows x 8 threads, 4 cols each
    {
      const int r = tid >> 3, sub = tid & 7, c = sub * 4;
      floatx4 sv = *reinterpret_cast<floatx4*>(&s_part[0][r][c]);
      sv += *reinterpret_cast<floatx4*>(&s_part[1][r][c]);
      float mx = fmaxf(fmaxf(sv[0], sv[1]), fmaxf(sv[2], sv[3]));
#pragma unroll
      for (int o = 1; o < 8; o <<= 1) mx = fmaxf(mx, __shfl_xor(mx, o));
      const float mo = m_lds[r];
      const float mn = fmaxf(mo, mx);
      floatx4 p;
      p[0] = __expf(sv[0] - mn); p[1] = __expf(sv[1] - mn);
      p[2] = __expf(sv[2] - mn); p[3] = __expf(sv[3] - mn);
      float rs = p[0] + p[1] + p[2] + p[3];
#pragma unroll
      for (int o = 1; o < 8; o <<= 1) rs += __shfl_xor(rs, o);
      if (sub == 0) {
        const float al = __expf(mo - mn);
        a_lds[r] = al; m_lds[r] = mn; l_lds[r] = l_lds[r] * al + rs;
      }
      half4 ph;
      ph[0] = (_Float16)p[0]; ph[1] = (_Float16)p[1];
      ph[2] = (_Float16)p[2]; ph[3] = (_Float16)p[3];
      *reinterpret_cast<half4*>(&p_lds[r][c]) = ph;
    }
    block_sync_lds();                       // b2

    // ---- O rescale + P A-frags + PV
    half8 pfr[4];
#pragma unroll
    for (int qs = 0; qs < 4; qs++) {
      floatx4 al = *reinterpret_cast<floatx4*>(&a_lds[qs * 16 + q4 * 4]);
#pragma unroll
      for (int j = 0; j < 4; j++) oacc[qs][j] *= al;
      pfr[qs] = *reinterpret_cast<const half8*>(&p_lds[qs * 16 + m15][q4 * 8]);
    }
#pragma unroll
    for (int j = 0; j < 4; j++)
#pragma unroll
      for (int qs = 0; qs < 4; qs++)
        oacc[qs][j] = __builtin_amdgcn_mfma_f32_16x16x32_f16(pfr[qs], vfr[j], oacc[qs][j], 0, 0, 0);
  };

  for (int t = 0; t < 32; t++) {
    tile_step(kbufA, kbufB, 2 * t);
    tile_step(kbufB, kbufA, 2 * t + 1);
  }

  // ---- epilogue: divide by l, store fp32 (64B-contiguous per (qs,j,r))
  const int q0 = qt * 64;
#pragma unroll
  for (int qs = 0; qs < 4; qs++) {
    floatx4 lv = *reinterpret_cast<floatx4*>(&l_lds[qs * 16 + q4 * 4]);
#pragma unroll
    for (int j = 0; j < 4; j++) {
      const int col = (w * 4 + j) * 16 + m15;
#pragma unroll
      for (int r = 0; r < 4; r++) {
        const int row = qs * 16 + q4 * 4 + r;
        out[((size_t)n * SEQ + q0 + row) * EDIM + col] = oacc[qs][j][r] / lv[r];
      }
    }
  }
}

// ---------------------------------------------------------------------------
// Fallback (ws too small): fp32 VALU attention, one block per query row.
// ---------------------------------------------------------------------------
__global__ void attn_fallback(const float* __restrict__ q, const float* __restrict__ k,
                              const float* __restrict__ v, float* __restrict__ out) {
  __shared__ float qrow[EDIM];
  __shared__ float sc[SEQ];
  __shared__ float red[16];
  const int tid = threadIdx.x;                    // 256
  const int n = blockIdx.x >> 11, qi = blockIdx.x & 2047;
  const int wv = tid >> 6, ln = tid & 63;
  const float* qp = q + ((size_t)n * SEQ + qi) * EDIM;
  for (int e = tid; e < EDIM; e += 256) qrow[e] = qp[e];
  __syncthreads();
  for (int kk = wv; kk < SEQ; kk += 4) {
    const float* kp = k + ((size_t)n * SEQ + kk) * EDIM;
    float s = 0.f;
    for (int e = ln; e < EDIM; e += 64) s = fmaf(qrow[e], kp[e], s);
    for (int o = 32; o > 0; o >>= 1) s += __shfl_down(s, o);
    if (ln == 0) sc[kk] = s;
  }
  __syncthreads();
  float mx = -3.0e38f;
  for (int kk = tid; kk < SEQ; kk += 256) mx = fmaxf(mx, sc[kk]);
  for (int o = 32; o > 0; o >>= 1) mx = fmaxf(mx, __shfl_down(mx, o));
  if (ln == 0) red[wv] = mx;
  __syncthreads();
  if (tid == 0) {
    float m2 = red[0];
    for (int i = 1; i < 4; i++) m2 = fmaxf(m2, red[i]);
    red[8] = m2;
  }
  __syncthreads();
  const float m = red[8];
  float ls = 0.f;
  for (int kk = tid; kk < SEQ; kk += 256) { float p = __expf(sc[kk] - m); sc[kk] = p; ls += p; }
  for (int o = 32; o > 0; o >>= 1) ls += __shfl_down(ls, o);
  if (ln == 0) red[wv] = ls;
  __syncthreads();
  if (tid == 0) { red[9] = red[0] + red[1] + red[2] + red[3]; }
  __syncthreads();
  const float linv = 1.f / red[9];
  for (int e = tid; e < EDIM; e += 256) {
    float acc = 0.f;
    const float* vp = v + ((size_t)n * SEQ) * EDIM + e;
    for (int kk = 0; kk < SEQ; kk++) acc = fmaf(sc[kk], vp[(size_t)kk * EDIM], acc);
    out[((size_t)n * SEQ + qi) * EDIM + e] = acc * linv;
  }
}

extern "C" void kernel_launch(void* const* d_in, const int* in_sizes, int n_in,
                              void* d_out, int out_size, void* d_ws, size_t ws_size,
                              hipStream_t stream) {
  const float* q = (const float*)d_in[0];
  const float* k = (const float*)d_in[1];
  const float* v = (const float*)d_in[2];
  float* out = (float*)d_out;
  const size_t need = 3 * NE * sizeof(_Float16);   // 50.3 MB
  if (ws_size >= need) {
    _Float16* qf = (_Float16*)d_ws;
    _Float16* kf = qf + NE;
    _Float16* vf = kf + NE;
    make_frags_qk<<<1024, 256, 0, stream>>>(q, k, qf, kf);
    make_frags_v<<<512, 256, 0, stream>>>(v, vf);
    attn_fused<<<256, 512, 0, stream>>>(qf, kf, vf, out);
  } else {
    attn_fallback<<<16384, 256, 0, stream>>>(q, k, v, out);
  }
}

// Round 6
// 286.098 us; speedup vs baseline: 2.6409x; 1.1253x over previous
//
#include <hip/hip_runtime.h>
#include <stdint.h>

// ---------------------------------------------------------------------------
// Attention: out = softmax(Q K^T) V,  N=8, S=2048, E=512, fp32 in/out.
// R6 = R5 + pre-pass fix: K-chunk dst offset must strip the tensor bit
// (R4/R5 wrote K frags into the V region and left kf poisoned -> absmax ~5).
// fp16 MFMA, operands pre-shuffled to fragment-lane order (1KB coalesced frag
// loads). R3-proven hazard order (S -> b1 -> softmax -> b2 -> PV).
// BQ=32, 512 blocks -> 2 blocks/CU (16 waves/CU) under a 128-VGPR budget.
// ---------------------------------------------------------------------------

typedef __attribute__((ext_vector_type(8))) _Float16 half8;   // MFMA A/B frag
typedef __attribute__((ext_vector_type(2))) _Float16 half2;
typedef __attribute__((ext_vector_type(4))) float    floatx4; // MFMA C/D frag

#define NBATCH 8
#define SEQ    2048
#define EDIM   512
static constexpr size_t NE = (size_t)NBATCH * SEQ * EDIM;  // 8388608 elems/tensor

// Barrier WITHOUT vmcnt drain: LDS ordering only; global loads in flight stay
// in flight (their consumers get compiler-inserted vmcnt waits).
__device__ __forceinline__ void block_sync_lds() {
  asm volatile("s_waitcnt lgkmcnt(0)\n\ts_barrier" ::: "memory");
}

// ---------------------------------------------------------------------------
// Fragment layout contract:
//  A/B-frag 16x16x32: lane l holds [dim16 = l&15][k = (l>>4)*8 + j].
//  Q/K: xf[((n*128 + rt)*16 + est)*512 + lane*8 + j]   (rt = row>>4, est = e>>5)
//  V:   vf[((n*64 + kt)*32 + et)*512 + lane*8 + j]     (kt = krow>>5, et = e>>4,
//        dim16 = e-col, k = krow within 32-tile)
// ---------------------------------------------------------------------------

// --- fused pre-pass: blocks [0,2048) Q/K direct gather; [2048,2560) V transpose.
__global__ void make_frags(const float* __restrict__ q, const float* __restrict__ k,
                           const float* __restrict__ v,
                           _Float16* __restrict__ qf, _Float16* __restrict__ kf,
                           _Float16* __restrict__ vf) {
  const int tid = threadIdx.x;
  if (blockIdx.x < 2048) {
#pragma unroll
    for (int i = 0; i < 4; i++) {
      const uint32_t c = blockIdx.x * 1024u + i * 256u + tid;
      const uint32_t ln = c & 63u, idx = c >> 6;
      const uint32_t est = idx & 15u, rt = (idx >> 4) & 127u;
      const uint32_t n = (idx >> 11) & 7u, tensor = idx >> 14;
      const float* src = (tensor ? k : q) +
          ((size_t)(n * SEQ + rt * 16 + (ln & 15u))) * EDIM + est * 32 + (ln >> 4) * 8;
      float4 a = *reinterpret_cast<const float4*>(src);
      float4 b = *reinterpret_cast<const float4*>(src + 4);
      half8 h;
      h[0] = (_Float16)a.x; h[1] = (_Float16)a.y; h[2] = (_Float16)a.z; h[3] = (_Float16)a.w;
      h[4] = (_Float16)b.x; h[5] = (_Float16)b.y; h[6] = (_Float16)b.z; h[7] = (_Float16)b.w;
      // c & 0xFFFFF: per-tensor chunk index (bit 20 = tensor selector — must
      // NOT leak into the offset; leaking it was the R4/R5 correctness bug).
      *reinterpret_cast<half8*>((tensor ? kf : qf) + (size_t)(c & 0xFFFFFu) * 8) = h;
    }
  } else {
    __shared__ float lds[32][260];
    const int b2 = blockIdx.x - 2048;       // 8 n x 64 kt
    const int n = b2 >> 6, kt = b2 & 63;
    const float* src = v + ((size_t)n * SEQ + kt * 32) * EDIM;
    _Float16* dst = vf + ((size_t)(n * 64 + kt) * 32) * 512;
#pragma unroll
    for (int eh = 0; eh < 2; eh++) {
      if (eh) __syncthreads();
#pragma unroll
      for (int i = 0; i < 8; i++) {         // stage 32 rows x 256 f32
        int c = i * 256 + tid;
        int row = c >> 6, col4 = c & 63;
        float4 x = *reinterpret_cast<const float4*>(src + (size_t)row * EDIM + eh * 256 + col4 * 4);
        *reinterpret_cast<float4*>(&lds[row][col4 * 4]) = x;
      }
      __syncthreads();
#pragma unroll
      for (int i = 0; i < 4; i++) {         // emit frag chunks
        int fl = i * 256 + tid;
        int etl = fl >> 6, ln = fl & 63;
        int m15 = ln & 15, q4 = ln >> 4;
        int e_local = etl * 16 + m15;
        half8 h;
#pragma unroll
        for (int j = 0; j < 8; j++) h[j] = (_Float16)lds[q4 * 8 + j][e_local];
        *reinterpret_cast<half8*>(dst + ((size_t)eh * 1024 + fl) * 8) = h;
      }
    }
  }
}

// ---------------------------------------------------------------------------
// Fused flash attention. Grid 512 = (n = blk&7, qt = blk>>3), 512 thr / 8 waves.
// BQ=32, BK=32, 64 K-tiles. Wave = (ks = w&1, es = w>>1):
//   S: both 16-q strips x its 16-krow half x 128-e quarter (K frags no-dup).
//   softmax: 32 rows x 16 thr, 2 cols each; 4-plane combine.
//   PV: wave owns 64-e slice (et = w*4..w*4+3).
// Per tile: S -> s_part -> b1 -> softmax -> b2 -> PV.
// LDS: 18432 + 2560 + 384 = 21376 B. __launch_bounds__(512,4) caps VGPR at
// 128 -> 2 blocks/CU; transient K/V frag loads keep peak live regs ~110.
// ---------------------------------------------------------------------------
__launch_bounds__(512, 4)
__global__ void attn_fused(const _Float16* __restrict__ qf, const _Float16* __restrict__ kf,
                           const _Float16* __restrict__ vf, float* __restrict__ out) {
  __shared__ float    s_part[4][32][36];   // 4 e-quarter partial scores
  __shared__ _Float16 p_lds[32][40];       // P fp16 (A-layout source)
  __shared__ float    m_lds[32], l_lds[32], a_lds[32];

  const int tid  = threadIdx.x;
  const int lane = tid & 63, w = tid >> 6;
  const int m15  = lane & 15, q4 = lane >> 4;
  const int n    = blockIdx.x & 7, qt = blockIdx.x >> 3;   // qt 0..63
  const int ks   = w & 1, es = w >> 1;

  if (tid < 32) { m_lds[tid] = -3.0e38f; l_lds[tid] = 0.0f; }

  // ---- Q fragments resident: 2 strips x 4 est (this wave's e-quarter). 32 VGPR.
  half8 qfr[2][4];
  {
    const uint32_t qbase = ((uint32_t)(n * 128 + qt * 2) * 16 + es * 4) * 512 + (uint32_t)lane * 8;
#pragma unroll
    for (int s = 0; s < 2; s++)
#pragma unroll
      for (int i = 0; i < 4; i++)
        qfr[s][i] = *reinterpret_cast<const half8*>(qf + qbase + (uint32_t)(s * 16 + i) * 512);
  }

  floatx4 oacc[2][4];                       // [strip][et_local], 32 regs (acc)
#pragma unroll
  for (int s = 0; s < 2; s++)
#pragma unroll
    for (int j = 0; j < 4; j++) oacc[s][j] = (floatx4){0.f, 0.f, 0.f, 0.f};

  uint32_t koff = ((uint32_t)(n * 128 + ks) * 16 + es * 4) * 512 + (uint32_t)lane * 8;
  uint32_t voff = ((uint32_t)(n * 64) * 32 + w * 4) * 512 + (uint32_t)lane * 8;

  block_sync_lds();                         // covers m/l init

  for (int t = 0; t < 64; t++) {
    // ---- S phase: K frags transient, direct global->reg (1KB coalesced each)
    half8 kfr[4];
#pragma unroll
    for (int i = 0; i < 4; i++)
      kfr[i] = *reinterpret_cast<const half8*>(kf + koff + (uint32_t)i * 512);
    koff += 16384;                          // 2 rt * 16 est * 512

    floatx4 sacc[2];
    sacc[0] = (floatx4){0.f, 0.f, 0.f, 0.f};
    sacc[1] = (floatx4){0.f, 0.f, 0.f, 0.f};
#pragma unroll
    for (int i = 0; i < 4; i++) {
      sacc[0] = __builtin_amdgcn_mfma_f32_16x16x32_f16(qfr[0][i], kfr[i], sacc[0], 0, 0, 0);
      sacc[1] = __builtin_amdgcn_mfma_f32_16x16x32_f16(qfr[1][i], kfr[i], sacc[1], 0, 0, 0);
    }
    // write partials (C-layout: row = q4*4+r, col = m15)
#pragma unroll
    for (int s = 0; s < 2; s++)
#pragma unroll
      for (int r = 0; r < 4; r++)
        s_part[es][s * 16 + q4 * 4 + r][ks * 16 + m15] = sacc[s][r];
    block_sync_lds();                       // b1

    // ---- softmax: 32 rows x 16 threads, 2 cols each
    {
      const int r = tid >> 4, sub = tid & 15, c = sub * 2;
      float svx = s_part[0][r][c],     svy = s_part[0][r][c + 1];
#pragma unroll
      for (int pl = 1; pl < 4; pl++) { svx += s_part[pl][r][c]; svy += s_part[pl][r][c + 1]; }
      float mx = fmaxf(svx, svy);
#pragma unroll
      for (int o = 1; o < 16; o <<= 1) mx = fmaxf(mx, __shfl_xor(mx, o));
      const float mo = m_lds[r];
      const float mn = fmaxf(mo, mx);
      const float px = __expf(svx - mn), py = __expf(svy - mn);
      float rs = px + py;
#pragma unroll
      for (int o = 1; o < 16; o <<= 1) rs += __shfl_xor(rs, o);
      if (sub == 0) {
        const float al = __expf(mo - mn);
        a_lds[r] = al; m_lds[r] = mn; l_lds[r] = l_lds[r] * al + rs;
      }
      half2 ph; ph[0] = (_Float16)px; ph[1] = (_Float16)py;
      *reinterpret_cast<half2*>(&p_lds[r][c]) = ph;
    }
    block_sync_lds();                       // b2

    // ---- PV phase: V frags transient, P A-frags from LDS, rescale, MFMA
    half8 vfr[4];
#pragma unroll
    for (int j = 0; j < 4; j++)
      vfr[j] = *reinterpret_cast<const half8*>(vf + voff + (uint32_t)j * 512);
    voff += 16384;                          // 32 et * 512

    half8 pfr[2];
    pfr[0] = *reinterpret_cast<const half8*>(&p_lds[m15][q4 * 8]);
    pfr[1] = *reinterpret_cast<const half8*>(&p_lds[16 + m15][q4 * 8]);
    {
      floatx4 al0 = *reinterpret_cast<floatx4*>(&a_lds[q4 * 4]);
      floatx4 al1 = *reinterpret_cast<floatx4*>(&a_lds[16 + q4 * 4]);
#pragma unroll
      for (int j = 0; j < 4; j++) { oacc[0][j] *= al0; oacc[1][j] *= al1; }
    }
#pragma unroll
    for (int j = 0; j < 4; j++) {
      oacc[0][j] = __builtin_amdgcn_mfma_f32_16x16x32_f16(pfr[0], vfr[j], oacc[0][j], 0, 0, 0);
      oacc[1][j] = __builtin_amdgcn_mfma_f32_16x16x32_f16(pfr[1], vfr[j], oacc[1][j], 0, 0, 0);
    }
  }

  // ---- epilogue: divide by l, store fp32 (l_lds final after last b2)
  const int q0 = qt * 32;
#pragma unroll
  for (int s = 0; s < 2; s++) {
    floatx4 lv = *reinterpret_cast<floatx4*>(&l_lds[s * 16 + q4 * 4]);
#pragma unroll
    for (int j = 0; j < 4; j++) {
      const int col = (w * 4 + j) * 16 + m15;
#pragma unroll
      for (int r = 0; r < 4; r++) {
        const int row = s * 16 + q4 * 4 + r;
        out[((size_t)n * SEQ + q0 + row) * EDIM + col] = oacc[s][j][r] / lv[r];
      }
    }
  }
}

// ---------------------------------------------------------------------------
// Fallback (ws too small): fp32 VALU attention, one block per query row.
// ---------------------------------------------------------------------------
__global__ void attn_fallback(const float* __restrict__ q, const float* __restrict__ k,
                              const float* __restrict__ v, float* __restrict__ out) {
  __shared__ float qrow[EDIM];
  __shared__ float sc[SEQ];
  __shared__ float red[16];
  const int tid = threadIdx.x;                    // 256
  const int n = blockIdx.x >> 11, qi = blockIdx.x & 2047;
  const int wv = tid >> 6, ln = tid & 63;
  const float* qp = q + ((size_t)n * SEQ + qi) * EDIM;
  for (int e = tid; e < EDIM; e += 256) qrow[e] = qp[e];
  __syncthreads();
  for (int kk = wv; kk < SEQ; kk += 4) {
    const float* kp = k + ((size_t)n * SEQ + kk) * EDIM;
    float s = 0.f;
    for (int e = ln; e < EDIM; e += 64) s = fmaf(qrow[e], kp[e], s);
    for (int o = 32; o > 0; o >>= 1) s += __shfl_down(s, o);
    if (ln == 0) sc[kk] = s;
  }
  __syncthreads();
  float mx = -3.0e38f;
  for (int kk = tid; kk < SEQ; kk += 256) mx = fmaxf(mx, sc[kk]);
  for (int o = 32; o > 0; o >>= 1) mx = fmaxf(mx, __shfl_down(mx, o));
  if (ln == 0) red[wv] = mx;
  __syncthreads();
  if (tid == 0) {
    float m2 = red[0];
    for (int i = 1; i < 4; i++) m2 = fmaxf(m2, red[i]);
    red[8] = m2;
  }
  __syncthreads();
  const float m = red[8];
  float ls = 0.f;
  for (int kk = tid; kk < SEQ; kk += 256) { float p = __expf(sc[kk] - m); sc[kk] = p; ls += p; }
  for (int o = 32; o > 0; o >>= 1) ls += __shfl_down(ls, o);
  if (ln == 0) red[wv] = ls;
  __syncthreads();
  if (tid == 0) { red[9] = red[0] + red[1] + red[2] + red[3]; }
  __syncthreads();
  const float linv = 1.f / red[9];
  for (int e = tid; e < EDIM; e += 256) {
    float acc = 0.f;
    const float* vp = v + ((size_t)n * SEQ) * EDIM + e;
    for (int kk = 0; kk < SEQ; kk++) acc = fmaf(sc[kk], vp[(size_t)kk * EDIM], acc);
    out[((size_t)n * SEQ + qi) * EDIM + e] = acc * linv;
  }
}

extern "C" void kernel_launch(void* const* d_in, const int* in_sizes, int n_in,
                              void* d_out, int out_size, void* d_ws, size_t ws_size,
                              hipStream_t stream) {
  const float* q = (const float*)d_in[0];
  const float* k = (const float*)d_in[1];
  const float* v = (const float*)d_in[2];
  float* out = (float*)d_out;
  const size_t need = 3 * NE * sizeof(_Float16);   // 50.3 MB
  if (ws_size >= need) {
    _Float16* qf = (_Float16*)d_ws;
    _Float16* kf = qf + NE;
    _Float16* vf = kf + NE;
    make_frags<<<2560, 256, 0, stream>>>(q, k, v, qf, kf, vf);
    attn_fused<<<512, 512, 0, stream>>>(qf, kf, vf, out);
  } else {
    attn_fallback<<<16384, 256, 0, stream>>>(q, k, v, out);
  }
}